// Round 9
// baseline (272.140 us; speedup 1.0000x reference)
//
#include <hip/hip_runtime.h>
#include <hip/hip_bf16.h>
#include <math.h>

#define NN   16
#define C_   128
#define HH   128
#define WW   128
#define CHID 32
#define NTILES 64     // one tile per output y-pair

#define BCHUNK 33792  // one B chunk: 4 rows * 132 px * 32 ci * 2B

typedef short bf16x8 __attribute__((ext_vector_type(8)));
typedef float f32x4  __attribute__((ext_vector_type(4)));

__device__ inline void glds16(const void* g, void* l) {
    __builtin_amdgcn_global_load_lds(
        (const __attribute__((address_space(1))) unsigned int*)g,
        (__attribute__((address_space(3))) unsigned int*)l, 16, 0, 0);
}

__device__ inline unsigned short f2bf(float f) {
    __hip_bfloat16 h = __float2bfloat16(f);
    return *reinterpret_cast<unsigned short*>(&h);
}

// ---------------------------------------------------------------------------
// Pack conv weights into 16x16x32 MFMA-A fragment-linear layout (bf16):
// wl[conv][kk 9][ck 4][cot 8][lane 64][8] ; value = W[co][ci][ky][kx]
// with co = cot*16 + (l&15), ci = ck*32 + (l>>4)*8 + j, kk = ky*3+kx. (R3)
__global__ __launch_bounds__(64) void pack_w_k(
    const float* __restrict__ w1, const float* __restrict__ w2,
    unsigned short* __restrict__ wl)
{
    const int b = blockIdx.x;                 // conv*288 + kk*32 + ck*8 + cot
    const int conv = b / 288, rem = b % 288;
    const int kk = rem / 32, ck = (rem % 32) / 8, cot = rem % 8;
    const int l = threadIdx.x;
    const int co  = cot * 16 + (l & 15);
    const int ci0 = ck * 32 + (l >> 4) * 8;
    const float* W = conv ? w2 : w1;
    union { unsigned short u[8]; uint4 v; } pk;
#pragma unroll
    for (int j = 0; j < 8; ++j)
        pk.u[j] = f2bf(W[(size_t)(co * C_ + ci0 + j) * 9 + kk]);
    unsigned short* dst = wl + (size_t)conv * 147456 +
        ((((size_t)kk * 4 + ck) * 8 + cot) * 64 + l) * 8;
    *reinterpret_cast<uint4*>(dst) = pk.v;
}

// ---------------------------------------------------------------------------
// fp32 NCHW -> bf16 ci16-slab NHWC: xb[n][y][slab 8][px 128][ci16]
__global__ __launch_bounds__(256) void to_cnhwc_k(
    const float* __restrict__ x, unsigned short* __restrict__ xb)
{
    __shared__ unsigned short s_t[128][136];   // row 272B = 17 x 16B slots
    const int y = blockIdx.x, n = blockIdx.y, t = threadIdx.x;

#pragma unroll
    for (int p = 0; p < 16; ++p) {
        int fi = p * 256 + t;                  // float4 index over [ci][x/4]
        int ci = fi >> 5, x0 = (fi & 31) * 4;
        float4 v = *reinterpret_cast<const float4*>(
            x + (((size_t)(n * C_ + ci) * HH) + y) * WW + x0);
        const int slot = ((ci >> 3) ^ ((x0 >> 2) & 7)) * 8 + (ci & 7);
        s_t[x0 + 0][slot] = f2bf(v.x);
        s_t[x0 + 1][slot] = f2bf(v.y);
        s_t[x0 + 2][slot] = f2bf(v.z);
        s_t[x0 + 3][slot] = f2bf(v.w);
    }
    __syncthreads();
    unsigned short* dstbase = xb + ((size_t)(n * HH + y)) * 16384;
#pragma unroll
    for (int p = 0; p < 8; ++p) {
        int o = p * 256 + t;                   // 16B unit: 2048 total
        int sl = o >> 8, u = o & 255;
        int xc = u >> 1, q = u & 1;
        int oct = sl * 2 + q;                  // ci-octet 0..15
        uint4 v = *reinterpret_cast<const uint4*>(
            &s_t[xc][(oct ^ ((xc >> 2) & 7)) * 8]);
        *reinterpret_cast<uint4*>(dstbase + (size_t)sl * 2048 + xc * 16 + q * 8) = v;
    }
}

// ---------------------------------------------------------------------------
// Implicit-GEMM 3x3 conv. Block: 128co x (2y x 128px). 8 waves, wave 64x64.
// Pipeline (R9): B chunks DOUBLE-BUFFERED (2 x 33.8KB LDS), stage(ck+1)
// issued at top of compute(ck), single barrier per chunk. A-fragments
// register-prefetched 2 kk ahead (covers ~300cyc L2 latency); B-fragments
// 1 kk ahead (covers LDS latency). 1 block/CU -> register budget 256/wave,
// ~184 used, occupancy unchanged vs R8.
// B tile slot-swizzled: row xi's 16B slot s holds ci-sub s ^ ((xi>>1)&3),
// staged from ci16-slab global layout via pre-swizzled per-lane source.
// MODE 0: bf16 ci16-NHWC out + PReLU (conv1).
// MODE 1: bf16 ci16-NHWC out + avg-pool partials (conv2 big-ws path).
// MODE 2: fp32 NCHW out + partials (conv2 fallback).
template<int MODE>
__global__ __launch_bounds__(512) void conv_mfma_k(
    const unsigned short* __restrict__ inb,   // bf16 ci16-slab NHWC
    const unsigned short* __restrict__ wl,    // this conv's packed frags
    const float* __restrict__ bias,
    const float* __restrict__ prelu_a,
    unsigned short* __restrict__ outb,        // MODE 0/1
    float* __restrict__ outf,                 // MODE 2
    float* __restrict__ partial)              // MODE 1/2
{
    __shared__ char  smem[2 * BCHUNK];        // B dbuf; repack overlays buf0
    __shared__ float s_part[8][64];

    const int tid = threadIdx.x;
    const int l = tid & 63, w = tid >> 6;
    const int wco = w >> 2, wy = (w >> 1) & 1, wxh = w & 1;
    const int lg = l >> 4, l15 = l & 15;
    const int yp = blockIdx.x, n = blockIdx.z;
    const int y0 = yp * 2;
    const int rot = (yp + n) & 3;

    const f32x4 fz = {0.f, 0.f, 0.f, 0.f};
    f32x4 acc[4][4];
#pragma unroll
    for (int m = 0; m < 4; ++m)
#pragma unroll
        for (int nf = 0; nf < 4; ++nf) acc[m][nf] = fz;

    const bf16x8* wv = reinterpret_cast<const bf16x8*>(wl);
    const uint4 z4 = {0u, 0u, 0u, 0u};

    // stage ci-chunk ck (32 ci) into buffer sb
    auto stage = [&](int ck, char* sb) {
        const int r = w >> 1, xh = w & 1;
        const int ygl = y0 - 1 + r;
        if (ygl < 0 || ygl >= HH) {
            int t2 = xh * 64 + l;
            for (int i = t2; i < 528; i += 128)
                *reinterpret_cast<uint4*>(sb + r * 8448 + i * 16) = z4;
        } else {
            if (xh == 0 && l < 8) {            // zero pad cols xi=0, xi=129
                int col = (l < 4) ? 0 : 129, q = l & 3;
                *reinterpret_cast<uint4*>(sb + r * 8448 + col * 64 + q * 16) = z4;
            }
            const size_t rowbase = ((size_t)(n * HH + ygl)) * 32768;
#pragma unroll
            for (int i = 0; i < 4; ++i) {
                // lane l -> pixel p, LDS slot (l&3); the 16B ci-sub stored at
                // slot s is s ^ f(1+p), f(xi)=(xi>>1)&3 -> pre-swizzle SOURCE.
                const int p  = xh * 64 + i * 16 + (l >> 2);
                const int sd = (l & 3) ^ (((1 + p) >> 1) & 3);
                const char* g = (const char*)inb + rowbase +
                    (size_t)(2 * ck + (sd >> 1)) * 4096 + p * 32 + (sd & 1) * 16;
                glds16(g, sb + r * 8448 + (1 + xh * 64 + i * 16) * 64);
            }
        }
    };

    stage(rot, smem);
    __syncthreads();

    for (int c8 = 0; c8 < 4; ++c8) {
        const int ck = (c8 + rot) & 3;
        char* buf = smem + (c8 & 1) * BCHUNK;
        // issue next chunk's staging into the other buffer (loads stay in
        // flight through the whole compute phase; drained by the barrier)
        if (c8 < 3) stage((c8 + 1 + rot) & 3, smem + ((c8 + 1) & 1) * BCHUNK);

        auto loadA = [&](int kk, bf16x8* a) {
#pragma unroll
            for (int m = 0; m < 4; ++m)
                a[m] = wv[(((size_t)kk * 4 + ck) * 8 + wco * 4 + m) * 64 + l];
        };
        auto rdB = [&](int kk, bf16x8* b) {
            const int ky = kk / 3, kx = kk % 3;
            const int rrow = wy + ky;
#pragma unroll
            for (int nf = 0; nf < 4; ++nf) {
                int xi = wxh * 64 + nf * 16 + l15 + kx;
                int slot = lg ^ ((xi >> 1) & 3);
                b[nf] = *reinterpret_cast<const bf16x8*>(
                    buf + rrow * 8448 + xi * 64 + slot * 16);
            }
        };

        // software pipeline: A 2-deep, B 1-deep register prefetch.
        bf16x8 ap[3][4], bp[2][4];
        loadA(0, ap[0]);
        loadA(1, ap[1]);
        rdB(0, bp[0]);
#pragma unroll
        for (int kk = 0; kk < 9; ++kk) {
            if (kk < 7) loadA(kk + 2, ap[(kk + 2) % 3]);
            if (kk < 8) rdB(kk + 1, bp[(kk + 1) & 1]);
            bf16x8* ac = ap[kk % 3];
            bf16x8* bc = bp[kk & 1];
#pragma unroll
            for (int nf = 0; nf < 4; ++nf)
#pragma unroll
                for (int m = 0; m < 4; ++m)
                    acc[m][nf] = __builtin_amdgcn_mfma_f32_16x16x32_bf16(
                        ac[m], bc[nf], acc[m][nf], 0, 0, 0);
        }
        __syncthreads();   // stage(ck+1) landed; buffer roles swap safely
    }

    // ---- epilogue (16x16 C/D: col px = l15, row co = wco*64+m*16+lg*4+jj) --
    const int ybase = y0 + wy;
    if (MODE == 0 || MODE == 1) {
        const float a1 = (MODE == 0) ? *prelu_a : 0.f;
        float ps[4][4];
        if (MODE == 1) {
#pragma unroll
            for (int m = 0; m < 4; ++m)
#pragma unroll
                for (int jj = 0; jj < 4; ++jj) ps[m][jj] = 0.f;
        }
        unsigned short (*s_rp)[136] = reinterpret_cast<unsigned short (*)[136]>(smem);
        for (int r = 0; r < 2; ++r) {
            if (wy == r) {
#pragma unroll
                for (int m = 0; m < 4; ++m) {
                    const int co0 = wco * 64 + m * 16 + lg * 4;
#pragma unroll
                    for (int nf = 0; nf < 4; ++nf) {
                        const int xc = wxh * 64 + nf * 16 + l15;
                        union { unsigned short u[4]; uint2 v; } pk;
#pragma unroll
                        for (int jj = 0; jj < 4; ++jj) {
                            float f = acc[m][nf][jj] + bias[co0 + jj];
                            if (MODE == 0) f = (f >= 0.f) ? f : a1 * f;
                            else           ps[m][jj] += f;
                            pk.u[jj] = f2bf(f);
                        }
                        *reinterpret_cast<uint2*>(&s_rp[xc][co0]) = pk.v;
                    }
                }
            }
            __syncthreads();
            const int y = y0 + r;
#pragma unroll
            for (int p = 0; p < 4; ++p) {
                int u = p * 512 + tid;         // 2048 16B units: [xc][k16]
                int xc = u >> 4, k = u & 15;
                uint4 v = *reinterpret_cast<const uint4*>(&s_rp[xc][k * 8]);
                *reinterpret_cast<uint4*>(outb +
                    (((size_t)(n * HH + y)) * 8 + (k >> 1)) * 2048 +
                    xc * 16 + (k & 1) * 8) = v;
            }
            __syncthreads();
        }
        if (MODE == 1) {
#pragma unroll
            for (int m = 0; m < 4; ++m)
#pragma unroll
                for (int jj = 0; jj < 4; ++jj) {
                    float s = ps[m][jj];
                    s += __shfl_xor(s, 1); s += __shfl_xor(s, 2);
                    s += __shfl_xor(s, 4); s += __shfl_xor(s, 8);
                    ps[m][jj] = s;
                }
            if (l15 == 0) {
#pragma unroll
                for (int m = 0; m < 4; ++m)
#pragma unroll
                    for (int jj = 0; jj < 4; ++jj)
                        s_part[w][m * 16 + lg * 4 + jj] = ps[m][jj];
            }
            __syncthreads();
            if (tid < C_) {
                const int half = tid >> 6;
                float s = 0.f;
#pragma unroll
                for (int w2 = 0; w2 < 4; ++w2) s += s_part[half * 4 + w2][tid & 63];
                partial[((size_t)(n * C_ + tid)) * NTILES + yp] = s;
            }
        }
    } else {
        float ps[4][4];
#pragma unroll
        for (int m = 0; m < 4; ++m)
#pragma unroll
            for (int jj = 0; jj < 4; ++jj) ps[m][jj] = 0.f;
#pragma unroll
        for (int m = 0; m < 4; ++m) {
            const int co0 = wco * 64 + m * 16 + lg * 4;
#pragma unroll
            for (int nf = 0; nf < 4; ++nf) {
                const int xc = wxh * 64 + nf * 16 + l15;
#pragma unroll
                for (int jj = 0; jj < 4; ++jj) {
                    float f = acc[m][nf][jj] + bias[co0 + jj];
                    outf[(((size_t)(n * C_ + co0 + jj)) * HH + ybase) * WW + xc] = f;
                    ps[m][jj] += f;
                }
            }
        }
#pragma unroll
        for (int m = 0; m < 4; ++m)
#pragma unroll
            for (int jj = 0; jj < 4; ++jj) {
                float s = ps[m][jj];
                s += __shfl_xor(s, 1); s += __shfl_xor(s, 2);
                s += __shfl_xor(s, 4); s += __shfl_xor(s, 8);
                ps[m][jj] = s;
            }
        if (l15 == 0) {
#pragma unroll
            for (int m = 0; m < 4; ++m)
#pragma unroll
                for (int jj = 0; jj < 4; ++jj)
                    s_part[w][m * 16 + lg * 4 + jj] = ps[m][jj];
        }
        __syncthreads();
        if (tid < C_) {
            const int half = tid >> 6;
            float s = 0.f;
#pragma unroll
            for (int w2 = 0; w2 < 4; ++w2) s += s_part[half * 4 + w2][tid & 63];
            partial[((size_t)(n * C_ + tid)) * NTILES + yp] = s;
        }
    }
}

// ---------------------------------------------------------------------------
// One block per sample: reduce partials -> x1, expert MLP, sigmoid gate.
__global__ __launch_bounds__(C_) void adapter_k(
    const float* __restrict__ partial, const int* __restrict__ intensity,
    const float* __restrict__ aW1, const float* __restrict__ ab1,
    const float* __restrict__ aW2, const float* __restrict__ ab2,
    float* __restrict__ sig)
{
    __shared__ float sx[C_];
    __shared__ float sa[CHID];
    const int n = blockIdx.x, c = threadIdx.x;

    float s = 0.f;
    for (int t = 0; t < NTILES; ++t)
        s += partial[(size_t)(n * C_ + c) * NTILES + t];
    sx[c] = s * (1.f / (float)(HH * WW));
    __syncthreads();

    const int idx = intensity[n] - 1;
    if (c < CHID) {
        float a = ab1[idx * CHID + c];
        const float* wrow = aW1 + (size_t)(idx * CHID + c) * C_;
        for (int k = 0; k < C_; ++k) a = fmaf(wrow[k], sx[k], a);
        sa[c] = fmaxf(a, 0.f);
    }
    __syncthreads();

    float g = ab2[idx * C_ + c];
    const float* w2row = aW2 + (size_t)(idx * C_ + c) * CHID;
#pragma unroll
    for (int k = 0; k < CHID; ++k) g = fmaf(w2row[k], sa[k], g);
    sig[n * C_ + c] = 1.f / (1.f + expf(-g));
}

// ---------------------------------------------------------------------------
// Big-ws epilogue: h (bf16 ci16-NHWC) + x (fp32 NCHW) -> out fp32 NCHW.
__global__ __launch_bounds__(256) void epilogue_bf16_k(
    const unsigned short* __restrict__ h2b, const float* __restrict__ x,
    const float* __restrict__ sig, const float* __restrict__ prelu_a,
    float* __restrict__ out)
{
    __shared__ unsigned short s_h[128][136];
    const int y = blockIdx.x, n = blockIdx.y, t = threadIdx.x;
    const float a = *prelu_a;
    const unsigned short* slab = h2b + ((size_t)(n * HH + y)) * 16384;

#pragma unroll
    for (int p = 0; p < 8; ++p) {
        int o = p * 256 + t;
        int sl = o >> 8, u = o & 255;
        int xc = u >> 1, q = u & 1;
        int oct = sl * 2 + q;
        uint4 v = *reinterpret_cast<const uint4*>(
            slab + (size_t)sl * 2048 + xc * 16 + q * 8);
        *reinterpret_cast<uint4*>(&s_h[xc][(oct ^ ((xc >> 2) & 7)) * 8]) = v;
    }
    __syncthreads();

#pragma unroll
    for (int p = 0; p < 16; ++p) {
        int fi = p * 256 + t;
        int ci = fi >> 5, x0 = (fi & 31) * 4;
        const float sg = sig[n * C_ + ci];
        float4 x4 = *reinterpret_cast<const float4*>(
            x + (((size_t)(n * C_ + ci)) * HH + y) * WW + x0);
        float4 v;
        float hv[4];
#pragma unroll
        for (int j = 0; j < 4; ++j) {
            int xr = x0 + j;
            unsigned short hu = s_h[xr][((ci >> 3) ^ ((xr >> 2) & 7)) * 8 + (ci & 7)];
            unsigned int bits = ((unsigned int)hu) << 16;
            hv[j] = *reinterpret_cast<float*>(&bits);
        }
        v.x = hv[0] * sg + x4.x;  v.x = (v.x >= 0.f) ? v.x : a * v.x;
        v.y = hv[1] * sg + x4.y;  v.y = (v.y >= 0.f) ? v.y : a * v.y;
        v.z = hv[2] * sg + x4.z;  v.z = (v.z >= 0.f) ? v.z : a * v.z;
        v.w = hv[3] * sg + x4.w;  v.w = (v.w >= 0.f) ? v.w : a * v.w;
        *reinterpret_cast<float4*>(
            out + (((size_t)(n * C_ + ci)) * HH + y) * WW + x0) = v;
    }
}

// ---------------------------------------------------------------------------
// Fallback epilogue: out = prelu(h * sig[n,c] + x, p2), in-place on d_out.
__global__ __launch_bounds__(256) void epilogue_k(
    const float* __restrict__ x, const float* __restrict__ sig,
    const float* __restrict__ prelu_a, float* __restrict__ out, int total4)
{
    const float a = *prelu_a;
    const int stride = gridDim.x * blockDim.x;
    for (int i = blockIdx.x * blockDim.x + threadIdx.x; i < total4; i += stride) {
        const int nc = (i * 4) >> 14;
        const float s = sig[nc];
        float4 h4 = ((const float4*)out)[i];
        float4 x4 = ((const float4*)x)[i];
        float4 v;
        v.x = h4.x * s + x4.x;  v.x = (v.x >= 0.f) ? v.x : a * v.x;
        v.y = h4.y * s + x4.y;  v.y = (v.y >= 0.f) ? v.y : a * v.y;
        v.z = h4.z * s + x4.z;  v.z = (v.z >= 0.f) ? v.z : a * v.z;
        v.w = h4.w * s + x4.w;  v.w = (v.w >= 0.f) ? v.w : a * v.w;
        ((float4*)out)[i] = v;
    }
}

// ---------------------------------------------------------------------------
extern "C" void kernel_launch(void* const* d_in, const int* in_sizes, int n_in,
                              void* d_out, int out_size, void* d_ws, size_t ws_size,
                              hipStream_t stream)
{
    const float* x         = (const float*)d_in[0];
    const int*   intensity = (const int*)  d_in[1];
    const float* w1        = (const float*)d_in[2];
    const float* b1        = (const float*)d_in[3];
    const float* p1        = (const float*)d_in[4];
    const float* w2        = (const float*)d_in[5];
    const float* b2        = (const float*)d_in[6];
    const float* aW1       = (const float*)d_in[7];
    const float* ab1       = (const float*)d_in[8];
    const float* aW2       = (const float*)d_in[9];
    const float* ab2       = (const float*)d_in[10];
    const float* p2        = (const float*)d_in[11];
    float* out = (float*)d_out;

    const size_t SLAB = (size_t)33554432 * 2;   // 67.1 MB (bf16 tensor)
    const size_t WLB  = (size_t)294912 * 2;     // packed weights bytes
    const size_t NEED = 2 * SLAB + WLB + (size_t)(NN * C_ * NTILES + NN * C_ + 64) * 4;
    const bool big = ws_size >= NEED;

    unsigned short* h1b = (unsigned short*)d_ws;
    unsigned short* xb;       // bf16 ci16-NHWC of x
    unsigned short* h2b = nullptr;
    unsigned short* wl;
    if (big) {
        xb  = (unsigned short*)((char*)d_ws + SLAB);   // aliased: xb then h2b
        h2b = xb;
        wl  = (unsigned short*)((char*)d_ws + 2 * SLAB);
    } else {
        xb  = (unsigned short*)d_out;                  // dead before conv2 writes
        wl  = (unsigned short*)((char*)d_ws + SLAB);
    }
    float* partial = (float*)((char*)wl + WLB);
    float* sig     = partial + (size_t)NN * C_ * NTILES;

    pack_w_k<<<dim3(576), dim3(64), 0, stream>>>(w1, w2, wl);
    to_cnhwc_k<<<dim3(HH, NN), dim3(256), 0, stream>>>(x, xb);

    conv_mfma_k<0><<<dim3(NTILES, 1, NN), dim3(512), 0, stream>>>(
        xb, wl, b1, p1, h1b, nullptr, nullptr);

    if (big) {
        conv_mfma_k<1><<<dim3(NTILES, 1, NN), dim3(512), 0, stream>>>(
            h1b, wl + (size_t)147456, b2, nullptr, h2b, nullptr, partial);
        adapter_k<<<dim3(NN), dim3(C_), 0, stream>>>(
            partial, intensity, aW1, ab1, aW2, ab2, sig);
        epilogue_bf16_k<<<dim3(HH, NN), dim3(256), 0, stream>>>(
            h2b, x, sig, p2, out);
    } else {
        conv_mfma_k<2><<<dim3(NTILES, 1, NN), dim3(512), 0, stream>>>(
            h1b, wl + (size_t)147456, b2, nullptr, nullptr, out, partial);
        adapter_k<<<dim3(NN), dim3(C_), 0, stream>>>(
            partial, intensity, aW1, ab1, aW2, ab2, sig);
        const int total4 = NN * C_ * HH * WW / 4;
        epilogue_k<<<dim3(2048), dim3(256), 0, stream>>>(x, sig, p2, out, total4);
    }
}

// Round 10
// 258.166 us; speedup vs baseline: 1.0541x; 1.0541x over previous
//
#include <hip/hip_runtime.h>
#include <hip/hip_bf16.h>
#include <math.h>

#define NN   16
#define C_   128
#define HH   128
#define WW   128
#define CHID 32
#define NTILES 32     // one tile per FOUR output rows

#define ROWB  8448    // LDS bytes per staged row: 132 px * 64B (32 ci bf16)
#define BUFB  50688   // one B buffer: 6 rows * ROWB

typedef short bf16x8 __attribute__((ext_vector_type(8)));
typedef float f32x4  __attribute__((ext_vector_type(4)));

__device__ inline void glds16(const void* g, void* l) {
    __builtin_amdgcn_global_load_lds(
        (const __attribute__((address_space(1))) unsigned int*)g,
        (__attribute__((address_space(3))) unsigned int*)l, 16, 0, 0);
}

__device__ inline unsigned short f2bf(float f) {
    __hip_bfloat16 h = __float2bfloat16(f);
    return *reinterpret_cast<unsigned short*>(&h);
}

// ---------------------------------------------------------------------------
// Pack conv weights into 16x16x32 MFMA-A fragment-linear layout (bf16):
// wl[conv][kk 9][ck 4][cot 8][lane 64][8] ; value = W[co][ci][ky][kx]
// with co = cot*16 + (l&15), ci = ck*32 + (l>>4)*8 + j, kk = ky*3+kx. (R3)
__global__ __launch_bounds__(64) void pack_w_k(
    const float* __restrict__ w1, const float* __restrict__ w2,
    unsigned short* __restrict__ wl)
{
    const int b = blockIdx.x;                 // conv*288 + kk*32 + ck*8 + cot
    const int conv = b / 288, rem = b % 288;
    const int kk = rem / 32, ck = (rem % 32) / 8, cot = rem % 8;
    const int l = threadIdx.x;
    const int co  = cot * 16 + (l & 15);
    const int ci0 = ck * 32 + (l >> 4) * 8;
    const float* W = conv ? w2 : w1;
    union { unsigned short u[8]; uint4 v; } pk;
#pragma unroll
    for (int j = 0; j < 8; ++j)
        pk.u[j] = f2bf(W[(size_t)(co * C_ + ci0 + j) * 9 + kk]);
    unsigned short* dst = wl + (size_t)conv * 147456 +
        ((((size_t)kk * 4 + ck) * 8 + cot) * 64 + l) * 8;
    *reinterpret_cast<uint4*>(dst) = pk.v;
}

// ---------------------------------------------------------------------------
// fp32 NCHW -> bf16 ci16-slab NHWC: xb[n][y][slab 8][px 128][ci16]
__global__ __launch_bounds__(256) void to_cnhwc_k(
    const float* __restrict__ x, unsigned short* __restrict__ xb)
{
    __shared__ unsigned short s_t[128][136];   // row 272B = 17 x 16B slots
    const int y = blockIdx.x, n = blockIdx.y, t = threadIdx.x;

#pragma unroll
    for (int p = 0; p < 16; ++p) {
        int fi = p * 256 + t;                  // float4 index over [ci][x/4]
        int ci = fi >> 5, x0 = (fi & 31) * 4;
        float4 v = *reinterpret_cast<const float4*>(
            x + (((size_t)(n * C_ + ci) * HH) + y) * WW + x0);
        const int slot = ((ci >> 3) ^ ((x0 >> 2) & 7)) * 8 + (ci & 7);
        s_t[x0 + 0][slot] = f2bf(v.x);
        s_t[x0 + 1][slot] = f2bf(v.y);
        s_t[x0 + 2][slot] = f2bf(v.z);
        s_t[x0 + 3][slot] = f2bf(v.w);
    }
    __syncthreads();
    unsigned short* dstbase = xb + ((size_t)(n * HH + y)) * 16384;
#pragma unroll
    for (int p = 0; p < 8; ++p) {
        int o = p * 256 + t;                   // 16B unit: 2048 total
        int sl = o >> 8, u = o & 255;
        int xc = u >> 1, q = u & 1;
        int oct = sl * 2 + q;                  // ci-octet 0..15
        uint4 v = *reinterpret_cast<const uint4*>(
            &s_t[xc][(oct ^ ((xc >> 2) & 7)) * 8]);
        *reinterpret_cast<uint4*>(dstbase + (size_t)sl * 2048 + xc * 16 + q * 8) = v;
    }
}

// ---------------------------------------------------------------------------
// Implicit-GEMM 3x3 conv (R10). Block: 128co x 4y x 128px at (n, yg).
// 8 waves = 2 wco x 4 wy ; wave tile 64co x 128px (m4 x nf8 of 16x16).
// A-traffic amortization: each A fragment now feeds 8 nf (was 4) -> VMEM
// A-path per CU halved. B tile 6 rows x 132px x 64B, double-buffered
// (2 x 50.7KB), stage(ck+1) issued before compute(ck). B reads keep the
// R3-proven 16-lane-span + slot-XOR pattern (0 conflicts).
// MODE 0: bf16 ci16-NHWC out + PReLU (conv1).
// MODE 1: bf16 ci16-NHWC out + avg-pool partials (conv2 big-ws path).
// MODE 2: fp32 NCHW out + partials (conv2 fallback).
template<int MODE>
__global__ __launch_bounds__(512) void conv_mfma_k(
    const unsigned short* __restrict__ inb,   // bf16 ci16-slab NHWC
    const unsigned short* __restrict__ wl,    // this conv's packed frags
    const float* __restrict__ bias,
    const float* __restrict__ prelu_a,
    unsigned short* __restrict__ outb,        // MODE 0/1
    float* __restrict__ outf,                 // MODE 2
    float* __restrict__ partial)              // MODE 1/2
{
    __shared__ char  smem[2 * BUFB];          // B dbuf; repack overlays buf0
    __shared__ float s_part[8][64];

    const int tid = threadIdx.x;
    const int l = tid & 63, w = tid >> 6;
    const int wco = w >> 2, wy = w & 3;
    const int lg = l >> 4, l15 = l & 15;
    const int yg = blockIdx.x, n = blockIdx.z;
    const int y0 = yg * 4;
    const int rot = (yg + n) & 3;

    const f32x4 fz = {0.f, 0.f, 0.f, 0.f};
    f32x4 acc[4][8];
#pragma unroll
    for (int m = 0; m < 4; ++m)
#pragma unroll
        for (int nf = 0; nf < 8; ++nf) acc[m][nf] = fz;

    const bf16x8* wv = reinterpret_cast<const bf16x8*>(wl);
    const uint4 z4 = {0u, 0u, 0u, 0u};

    // stage ci-chunk ck (32 ci, rows y0-1..y0+4) into buffer sb.
    // 48 groups of 64 16B-units; wave w handles groups w, w+8, ..., w+40.
    auto stage = [&](int ck, char* sb) {
        if (tid < 48) {                        // zero pads: cols xi=0, xi=129
            const int r = tid >> 3, col = ((tid >> 2) & 1) ? 129 : 0, q = tid & 3;
            *reinterpret_cast<uint4*>(sb + r * ROWB + col * 64 + q * 16) = z4;
        }
#pragma unroll
        for (int i = 0; i < 6; ++i) {
            const int g   = w + i * 8;         // 0..47
            const int row = g >> 3, seg = g & 7;
            const int ygl = y0 - 1 + row;
            char* dst = sb + row * ROWB + (1 + seg * 16) * 64;
            if (ygl < 0 || ygl >= HH) {
                *reinterpret_cast<uint4*>(dst + l * 16) = z4;
            } else {
                const int p  = seg * 16 + (l >> 2);
                const int sd = (l & 3) ^ (((1 + p) >> 1) & 3);
                const char* g_src = (const char*)inb +
                    ((size_t)(n * HH + ygl)) * 32768 +
                    (size_t)(2 * ck + (sd >> 1)) * 4096 + p * 32 + (sd & 1) * 16;
                glds16(g_src, dst);
            }
        }
    };

    stage(rot, smem);
    __syncthreads();

    for (int c8 = 0; c8 < 4; ++c8) {
        const int ck = (c8 + rot) & 3;
        char* buf = smem + (c8 & 1) * BUFB;
        if (c8 < 3) stage((c8 + 1 + rot) & 3, smem + ((c8 + 1) & 1) * BUFB);

        // ---- compute: 9 shifted GEMMs; A prefetched one kk ahead ----
        bf16x8 a_cur[4];
#pragma unroll
        for (int m = 0; m < 4; ++m)
            a_cur[m] = wv[(((size_t)0 * 4 + ck) * 8 + wco * 4 + m) * 64 + l];

#pragma unroll
        for (int kk = 0; kk < 9; ++kk) {
            const int ky = kk / 3, kx = kk % 3;
            bf16x8 a_nxt[4];
            if (kk < 8) {
#pragma unroll
                for (int m = 0; m < 4; ++m)
                    a_nxt[m] = wv[((((size_t)kk + 1) * 4 + ck) * 8 + wco * 4 + m) * 64 + l];
            }
            const int rrow = wy + ky;
            bf16x8 b[8];
#pragma unroll
            for (int nf = 0; nf < 8; ++nf) {
                int xi = nf * 16 + l15 + kx;
                int slot = lg ^ ((xi >> 1) & 3);
                b[nf] = *reinterpret_cast<const bf16x8*>(
                    buf + rrow * ROWB + xi * 64 + slot * 16);
            }
#pragma unroll
            for (int nf = 0; nf < 8; ++nf)
#pragma unroll
                for (int m = 0; m < 4; ++m)
                    acc[m][nf] = __builtin_amdgcn_mfma_f32_16x16x32_bf16(
                        a_cur[m], b[nf], acc[m][nf], 0, 0, 0);
            if (kk < 8) {
#pragma unroll
                for (int m = 0; m < 4; ++m) a_cur[m] = a_nxt[m];
            }
        }
        __syncthreads();   // stage(ck+1) landed; buffer roles swap safely
    }

    // ---- epilogue (16x16 C/D: col px = l15, row co = wco*64+m*16+lg*4+jj) --
    if (MODE == 0 || MODE == 1) {
        const float a1 = (MODE == 0) ? *prelu_a : 0.f;
        float ps[4][4];
        if (MODE == 1) {
#pragma unroll
            for (int m = 0; m < 4; ++m)
#pragma unroll
                for (int jj = 0; jj < 4; ++jj) ps[m][jj] = 0.f;
        }
        unsigned short (*s_rp)[136] = reinterpret_cast<unsigned short (*)[136]>(smem);
        for (int r = 0; r < 4; ++r) {
            if (wy == r) {
#pragma unroll
                for (int m = 0; m < 4; ++m) {
                    const int co0 = wco * 64 + m * 16 + lg * 4;
#pragma unroll
                    for (int nf = 0; nf < 8; ++nf) {
                        const int xc = nf * 16 + l15;
                        union { unsigned short u[4]; uint2 v; } pk;
#pragma unroll
                        for (int jj = 0; jj < 4; ++jj) {
                            float f = acc[m][nf][jj] + bias[co0 + jj];
                            if (MODE == 0) f = (f >= 0.f) ? f : a1 * f;
                            else           ps[m][jj] += f;
                            pk.u[jj] = f2bf(f);
                        }
                        *reinterpret_cast<uint2*>(&s_rp[xc][co0]) = pk.v;
                    }
                }
            }
            __syncthreads();
            const int y = y0 + r;
#pragma unroll
            for (int p = 0; p < 4; ++p) {
                int u = p * 512 + tid;         // 2048 16B units: [xc][k16]
                int xc = u >> 4, k = u & 15;
                uint4 v = *reinterpret_cast<const uint4*>(&s_rp[xc][k * 8]);
                *reinterpret_cast<uint4*>(outb +
                    (((size_t)(n * HH + y)) * 8 + (k >> 1)) * 2048 +
                    xc * 16 + (k & 1) * 8) = v;
            }
            __syncthreads();
        }
        if (MODE == 1) {
#pragma unroll
            for (int m = 0; m < 4; ++m)
#pragma unroll
                for (int jj = 0; jj < 4; ++jj) {
                    float s = ps[m][jj];
                    s += __shfl_xor(s, 1); s += __shfl_xor(s, 2);
                    s += __shfl_xor(s, 4); s += __shfl_xor(s, 8);
                    ps[m][jj] = s;
                }
            if (l15 == 0) {
#pragma unroll
                for (int m = 0; m < 4; ++m)
#pragma unroll
                    for (int jj = 0; jj < 4; ++jj)
                        s_part[w][m * 16 + lg * 4 + jj] = ps[m][jj];
            }
            __syncthreads();
            if (tid < C_) {
                const int half = tid >> 6;
                float s = 0.f;
#pragma unroll
                for (int w2 = 0; w2 < 4; ++w2) s += s_part[half * 4 + w2][tid & 63];
                partial[((size_t)(n * C_ + tid)) * NTILES + yg] = s;
            }
        }
    } else {
        const int ybase = y0 + wy;
        float ps[4][4];
#pragma unroll
        for (int m = 0; m < 4; ++m)
#pragma unroll
            for (int jj = 0; jj < 4; ++jj) ps[m][jj] = 0.f;
#pragma unroll
        for (int m = 0; m < 4; ++m) {
            const int co0 = wco * 64 + m * 16 + lg * 4;
#pragma unroll
            for (int nf = 0; nf < 8; ++nf) {
                const int xc = nf * 16 + l15;
#pragma unroll
                for (int jj = 0; jj < 4; ++jj) {
                    float f = acc[m][nf][jj] + bias[co0 + jj];
                    outf[(((size_t)(n * C_ + co0 + jj)) * HH + ybase) * WW + xc] = f;
                    ps[m][jj] += f;
                }
            }
        }
#pragma unroll
        for (int m = 0; m < 4; ++m)
#pragma unroll
            for (int jj = 0; jj < 4; ++jj) {
                float s = ps[m][jj];
                s += __shfl_xor(s, 1); s += __shfl_xor(s, 2);
                s += __shfl_xor(s, 4); s += __shfl_xor(s, 8);
                ps[m][jj] = s;
            }
        if (l15 == 0) {
#pragma unroll
            for (int m = 0; m < 4; ++m)
#pragma unroll
                for (int jj = 0; jj < 4; ++jj)
                    s_part[w][m * 16 + lg * 4 + jj] = ps[m][jj];
        }
        __syncthreads();
        if (tid < C_) {
            const int half = tid >> 6;
            float s = 0.f;
#pragma unroll
            for (int w2 = 0; w2 < 4; ++w2) s += s_part[half * 4 + w2][tid & 63];
            partial[((size_t)(n * C_ + tid)) * NTILES + yg] = s;
        }
    }
}

// ---------------------------------------------------------------------------
// One block per sample: reduce partials -> x1, expert MLP, sigmoid gate.
__global__ __launch_bounds__(C_) void adapter_k(
    const float* __restrict__ partial, const int* __restrict__ intensity,
    const float* __restrict__ aW1, const float* __restrict__ ab1,
    const float* __restrict__ aW2, const float* __restrict__ ab2,
    float* __restrict__ sig)
{
    __shared__ float sx[C_];
    __shared__ float sa[CHID];
    const int n = blockIdx.x, c = threadIdx.x;

    float s = 0.f;
    for (int t = 0; t < NTILES; ++t)
        s += partial[(size_t)(n * C_ + c) * NTILES + t];
    sx[c] = s * (1.f / (float)(HH * WW));
    __syncthreads();

    const int idx = intensity[n] - 1;
    if (c < CHID) {
        float a = ab1[idx * CHID + c];
        const float* wrow = aW1 + (size_t)(idx * CHID + c) * C_;
        for (int k = 0; k < C_; ++k) a = fmaf(wrow[k], sx[k], a);
        sa[c] = fmaxf(a, 0.f);
    }
    __syncthreads();

    float g = ab2[idx * C_ + c];
    const float* w2row = aW2 + (size_t)(idx * C_ + c) * CHID;
#pragma unroll
    for (int k = 0; k < CHID; ++k) g = fmaf(w2row[k], sa[k], g);
    sig[n * C_ + c] = 1.f / (1.f + expf(-g));
}

// ---------------------------------------------------------------------------
// Big-ws epilogue: h (bf16 ci16-NHWC) + x (fp32 NCHW) -> out fp32 NCHW.
__global__ __launch_bounds__(256) void epilogue_bf16_k(
    const unsigned short* __restrict__ h2b, const float* __restrict__ x,
    const float* __restrict__ sig, const float* __restrict__ prelu_a,
    float* __restrict__ out)
{
    __shared__ unsigned short s_h[128][136];
    const int y = blockIdx.x, n = blockIdx.y, t = threadIdx.x;
    const float a = *prelu_a;
    const unsigned short* slab = h2b + ((size_t)(n * HH + y)) * 16384;

#pragma unroll
    for (int p = 0; p < 8; ++p) {
        int o = p * 256 + t;
        int sl = o >> 8, u = o & 255;
        int xc = u >> 1, q = u & 1;
        int oct = sl * 2 + q;
        uint4 v = *reinterpret_cast<const uint4*>(
            slab + (size_t)sl * 2048 + xc * 16 + q * 8);
        *reinterpret_cast<uint4*>(&s_h[xc][(oct ^ ((xc >> 2) & 7)) * 8]) = v;
    }
    __syncthreads();

#pragma unroll
    for (int p = 0; p < 16; ++p) {
        int fi = p * 256 + t;
        int ci = fi >> 5, x0 = (fi & 31) * 4;
        const float sg = sig[n * C_ + ci];
        float4 x4 = *reinterpret_cast<const float4*>(
            x + (((size_t)(n * C_ + ci)) * HH + y) * WW + x0);
        float4 v;
        float hv[4];
#pragma unroll
        for (int j = 0; j < 4; ++j) {
            int xr = x0 + j;
            unsigned short hu = s_h[xr][((ci >> 3) ^ ((xr >> 2) & 7)) * 8 + (ci & 7)];
            unsigned int bits = ((unsigned int)hu) << 16;
            hv[j] = *reinterpret_cast<float*>(&bits);
        }
        v.x = hv[0] * sg + x4.x;  v.x = (v.x >= 0.f) ? v.x : a * v.x;
        v.y = hv[1] * sg + x4.y;  v.y = (v.y >= 0.f) ? v.y : a * v.y;
        v.z = hv[2] * sg + x4.z;  v.z = (v.z >= 0.f) ? v.z : a * v.z;
        v.w = hv[3] * sg + x4.w;  v.w = (v.w >= 0.f) ? v.w : a * v.w;
        *reinterpret_cast<float4*>(
            out + (((size_t)(n * C_ + ci)) * HH + y) * WW + x0) = v;
    }
}

// ---------------------------------------------------------------------------
// Fallback epilogue: out = prelu(h * sig[n,c] + x, p2), in-place on d_out.
__global__ __launch_bounds__(256) void epilogue_k(
    const float* __restrict__ x, const float* __restrict__ sig,
    const float* __restrict__ prelu_a, float* __restrict__ out, int total4)
{
    const float a = *prelu_a;
    const int stride = gridDim.x * blockDim.x;
    for (int i = blockIdx.x * blockDim.x + threadIdx.x; i < total4; i += stride) {
        const int nc = (i * 4) >> 14;
        const float s = sig[nc];
        float4 h4 = ((const float4*)out)[i];
        float4 x4 = ((const float4*)x)[i];
        float4 v;
        v.x = h4.x * s + x4.x;  v.x = (v.x >= 0.f) ? v.x : a * v.x;
        v.y = h4.y * s + x4.y;  v.y = (v.y >= 0.f) ? v.y : a * v.y;
        v.z = h4.z * s + x4.z;  v.z = (v.z >= 0.f) ? v.z : a * v.z;
        v.w = h4.w * s + x4.w;  v.w = (v.w >= 0.f) ? v.w : a * v.w;
        ((float4*)out)[i] = v;
    }
}

// ---------------------------------------------------------------------------
extern "C" void kernel_launch(void* const* d_in, const int* in_sizes, int n_in,
                              void* d_out, int out_size, void* d_ws, size_t ws_size,
                              hipStream_t stream)
{
    const float* x         = (const float*)d_in[0];
    const int*   intensity = (const int*)  d_in[1];
    const float* w1        = (const float*)d_in[2];
    const float* b1        = (const float*)d_in[3];
    const float* p1        = (const float*)d_in[4];
    const float* w2        = (const float*)d_in[5];
    const float* b2        = (const float*)d_in[6];
    const float* aW1       = (const float*)d_in[7];
    const float* ab1       = (const float*)d_in[8];
    const float* aW2       = (const float*)d_in[9];
    const float* ab2       = (const float*)d_in[10];
    const float* p2        = (const float*)d_in[11];
    float* out = (float*)d_out;

    const size_t SLAB = (size_t)33554432 * 2;   // 67.1 MB (bf16 tensor)
    const size_t WLB  = (size_t)294912 * 2;     // packed weights bytes
    const size_t NEED = 2 * SLAB + WLB + (size_t)(NN * C_ * NTILES + NN * C_ + 64) * 4;
    const bool big = ws_size >= NEED;

    unsigned short* h1b = (unsigned short*)d_ws;
    unsigned short* xb;       // bf16 ci16-NHWC of x
    unsigned short* h2b = nullptr;
    unsigned short* wl;
    if (big) {
        xb  = (unsigned short*)((char*)d_ws + SLAB);   // aliased: xb then h2b
        h2b = xb;
        wl  = (unsigned short*)((char*)d_ws + 2 * SLAB);
    } else {
        xb  = (unsigned short*)d_out;                  // dead before conv2 writes
        wl  = (unsigned short*)((char*)d_ws + SLAB);
    }
    float* partial = (float*)((char*)wl + WLB);
    float* sig     = partial + (size_t)NN * C_ * NTILES;

    pack_w_k<<<dim3(576), dim3(64), 0, stream>>>(w1, w2, wl);
    to_cnhwc_k<<<dim3(HH, NN), dim3(256), 0, stream>>>(x, xb);

    conv_mfma_k<0><<<dim3(NTILES, 1, NN), dim3(512), 0, stream>>>(
        xb, wl, b1, p1, h1b, nullptr, nullptr);

    if (big) {
        conv_mfma_k<1><<<dim3(NTILES, 1, NN), dim3(512), 0, stream>>>(
            h1b, wl + (size_t)147456, b2, nullptr, h2b, nullptr, partial);
        adapter_k<<<dim3(NN), dim3(C_), 0, stream>>>(
            partial, intensity, aW1, ab1, aW2, ab2, sig);
        epilogue_bf16_k<<<dim3(HH, NN), dim3(256), 0, stream>>>(
            h2b, x, sig, p2, out);
    } else {
        conv_mfma_k<2><<<dim3(NTILES, 1, NN), dim3(512), 0, stream>>>(
            h1b, wl + (size_t)147456, b2, nullptr, nullptr, out, partial);
        adapter_k<<<dim3(NN), dim3(C_), 0, stream>>>(
            partial, intensity, aW1, ab1, aW2, ab2, sig);
        const int total4 = NN * C_ * HH * WW / 4;
        epilogue_k<<<dim3(2048), dim3(256), 0, stream>>>(x, sig, p2, out, total4);
    }
}